// Round 4
// baseline (1347.531 us; speedup 1.0000x reference)
//
#include <hip/hip_runtime.h>
#include <hip/hip_cooperative_groups.h>
#include <math.h>

// Problem constants (reference: N=256, D=512, H=512, EPS=1.0)
#define NB   256
#define DD   512
#define HH   512
#define NH   (NB * HH)        // 131072
#define K3H  1536
#define CG_ITERS 16

typedef __attribute__((ext_vector_type(8))) short   short8v;   // 8 x bf16 (4 VGPR)
typedef __attribute__((ext_vector_type(4))) float   f32x4;     // MFMA acc
typedef __attribute__((ext_vector_type(4))) unsigned short ushort4v;
typedef __attribute__((ext_vector_type(2))) unsigned short ushort2v;

__device__ __forceinline__ float sigmoidf_(float v) { return 1.0f / (1.0f + expf(-v)); }

// fp32 -> bf16 round-to-nearest-even
__device__ __forceinline__ unsigned short f2bf(float f) {
    union { float f; unsigned int u; } v; v.f = f;
    return (unsigned short)((v.u + 0x7FFFu + ((v.u >> 16) & 1u)) >> 16);
}
__device__ __forceinline__ float bf2f(unsigned short h) {
    union { unsigned int u; float f; } v; v.u = ((unsigned int)h) << 16;
    return v.f;
}

// Swizzled LDS index (in shorts) for 64-col bf16 rows, 16B slots: <=2-way (free).
__device__ __forceinline__ int swz(int row, int col8) {
    return row * 64 + ((col8 ^ (row & 7)) << 3);
}

__device__ __forceinline__ void gatecalc(float zi, float zf, float zg, float zo, float cxv,
                                         float& hn, float& cn, float& ci, float& cf, float& cg_) {
    const float iv = sigmoidf_(zi), fv = sigmoidf_(zf), gv = tanhf(zg), ov = sigmoidf_(zo);
    cn  = fv * cxv + iv * gv;
    hn  = ov * tanhf(cn);
    ci  = iv * (1.0f - iv) * gv;
    cf  = fv * (1.0f - fv) * cxv;
    cg_ = (1.0f - gv * gv) * iv;
}

// ---------------------------------------------------------------------------
// Prep A: fp32 -> bf16 for Wih(2048x512), Whh(2048x512), x, hx.  2304 blocks.
// ---------------------------------------------------------------------------
__global__ __launch_bounds__(256) void k_cvt(
    const float* __restrict__ Wih, const float* __restrict__ Whh,
    const float* __restrict__ x, const float* __restrict__ hx,
    unsigned short* __restrict__ Wihb, unsigned short* __restrict__ Whhb,
    unsigned short* __restrict__ xb, unsigned short* __restrict__ hxb)
{
    const int idx = (blockIdx.x * 256 + threadIdx.x) * 4;   // 2,359,296 total elems
    const float* src; unsigned short* dst; int off;
    if      (idx < 1048576) { src = Wih; dst = Wihb; off = idx; }
    else if (idx < 2097152) { src = Whh; dst = Whhb; off = idx - 1048576; }
    else if (idx < 2228224) { src = x;   dst = xb;   off = idx - 2097152; }
    else                    { src = hx;  dst = hxb;  off = idx - 2228224; }
    float4 v = *(const float4*)(src + off);
    ushort4v o;
    o[0] = f2bf(v.x); o[1] = f2bf(v.y); o[2] = f2bf(v.z); o[3] = f2bf(v.w);
    *(ushort4v*)(dst + off) = o;
}

// ---------------------------------------------------------------------------
// Prep B (MFMA): M = W13 @ W13^T  (1536x1536), W13 = first 1536 rows of Wih.
// Stored as bf16 hi/lo pair (fp32-accurate operator). Grid 24*24=576 blocks.
// ---------------------------------------------------------------------------
__global__ __launch_bounds__(256) void k_gemm_m(
    const unsigned short* __restrict__ Wihb,
    unsigned short* __restrict__ Mhi, unsigned short* __restrict__ Mlo)
{
    __shared__ unsigned short As[4096];
    __shared__ unsigned short Bs[4096];
    const int r0 = (blockIdx.x / 24) * 64;
    const int c0 = (blockIdx.x % 24) * 64;
    const int t = threadIdx.x;
    const int w = t >> 6, lane = t & 63;
    const int wm = (w >> 1) * 32, wc = (w & 1) * 32;
    const int fr = lane & 15, g = lane >> 4;
    const int srow = t >> 3, scol8 = t & 7;
    f32x4 acc[2][2] = {};
    for (int st = 0; st < 8; ++st) {
        const int kk = st * 64;
        #pragma unroll
        for (int pp = 0; pp < 2; ++pp) {
            const int row = pp * 32 + srow;
            *(short8v*)&As[swz(row, scol8)] =
                *(const short8v*)(Wihb + (size_t)(r0 + row) * DD + kk + scol8 * 8);
            *(short8v*)&Bs[swz(row, scol8)] =
                *(const short8v*)(Wihb + (size_t)(c0 + row) * DD + kk + scol8 * 8);
        }
        __syncthreads();
        #pragma unroll
        for (int ks2 = 0; ks2 < 2; ++ks2) {
            short8v a[2], b[2];
            #pragma unroll
            for (int i = 0; i < 2; ++i) {
                a[i] = *(const short8v*)&As[swz(wm + i * 16 + fr, ks2 * 4 + g)];
                b[i] = *(const short8v*)&Bs[swz(wc + i * 16 + fr, ks2 * 4 + g)];
            }
            #pragma unroll
            for (int i = 0; i < 2; ++i)
                #pragma unroll
                for (int jj = 0; jj < 2; ++jj)
                    acc[i][jj] = __builtin_amdgcn_mfma_f32_16x16x32_bf16(a[i], b[jj], acc[i][jj], 0, 0, 0);
        }
        __syncthreads();
    }
    #pragma unroll
    for (int i = 0; i < 2; ++i)
        #pragma unroll
        for (int jj = 0; jj < 2; ++jj)
            #pragma unroll
            for (int rg = 0; rg < 4; ++rg) {
                const int r = r0 + wm + i * 16 + g * 4 + rg;
                const int c = c0 + wc + jj * 16 + fr;
                const float v = acc[i][jj][rg];
                const unsigned short h = f2bf(v);
                Mhi[(size_t)r * K3H + c] = h;
                Mlo[(size_t)r * K3H + c] = f2bf(v - bf2f(h));
            }
}

// ---------------------------------------------------------------------------
// Cooperative kernel: phase Z (z GEMM) -> phase G (gates + CG init) ->
// 16 x { phase A: V = U @ (Mhi+Mlo)^T ; phase B: per-row CG update }.
// Grid 256 x 256 threads (1 block/CU). CG state x,r,p,ca live in registers.
// ---------------------------------------------------------------------------
__global__ __launch_bounds__(256) void k_coop(
    const unsigned short* __restrict__ xb, const unsigned short* __restrict__ hxb,
    const unsigned short* __restrict__ Wihb, const unsigned short* __restrict__ Whhb,
    const float* __restrict__ cx, const float* __restrict__ bih, const float* __restrict__ bhh,
    float* __restrict__ zp, unsigned short* __restrict__ U,
    const unsigned short* __restrict__ Mhi, const unsigned short* __restrict__ Mlo,
    float* __restrict__ Vp, float* __restrict__ out)
{
    cooperative_groups::grid_group grid = cooperative_groups::this_grid();
    __shared__ unsigned short As[4096];
    __shared__ unsigned short Bh[4096];
    __shared__ unsigned short Bl[4096];
    __shared__ float red[256];
    __shared__ float sA, sB2, sRho;
    const int bid = blockIdx.x, t = threadIdx.x;
    const int w = t >> 6, lane = t & 63;
    const int wm = (w >> 1) * 32, wj = (w & 1) * 32;
    const int fr = lane & 15, g = lane >> 4;
    const int srow = t >> 3, scol8 = t & 7;

    // ---------------- Phase Z: zp[ks][n][c], 256 blocks ----------------
    {
        const int ks = bid & 1;
        const int n0 = ((bid >> 1) & 3) * 64;
        const int c0 = (bid >> 3) * 64;
        const unsigned short* Asrc = ks ? hxb : xb;
        const unsigned short* Bsrc = ks ? Whhb : Wihb;
        f32x4 acc[2][2] = {};
        for (int st = 0; st < 8; ++st) {
            const int kk = st * 64;
            #pragma unroll
            for (int pp = 0; pp < 2; ++pp) {
                const int row = pp * 32 + srow;
                *(short8v*)&As[swz(row, scol8)] =
                    *(const short8v*)(Asrc + (size_t)(n0 + row) * DD + kk + scol8 * 8);
                *(short8v*)&Bh[swz(row, scol8)] =
                    *(const short8v*)(Bsrc + (size_t)(c0 + row) * DD + kk + scol8 * 8);
            }
            __syncthreads();
            #pragma unroll
            for (int ks2 = 0; ks2 < 2; ++ks2) {
                short8v a[2], b[2];
                #pragma unroll
                for (int i = 0; i < 2; ++i) {
                    a[i] = *(const short8v*)&As[swz(wm + i * 16 + fr, ks2 * 4 + g)];
                    b[i] = *(const short8v*)&Bh[swz(wj + i * 16 + fr, ks2 * 4 + g)];
                }
                #pragma unroll
                for (int i = 0; i < 2; ++i)
                    #pragma unroll
                    for (int jj = 0; jj < 2; ++jj)
                        acc[i][jj] = __builtin_amdgcn_mfma_f32_16x16x32_bf16(a[i], b[jj], acc[i][jj], 0, 0, 0);
            }
            __syncthreads();
        }
        float* Z = zp + (size_t)ks * NB * 2048;
        #pragma unroll
        for (int i = 0; i < 2; ++i)
            #pragma unroll
            for (int jj = 0; jj < 2; ++jj)
                #pragma unroll
                for (int rg = 0; rg < 4; ++rg) {
                    const int n = n0 + wm + i * 16 + g * 4 + rg;
                    const int c = c0 + wj + jj * 16 + fr;
                    Z[(size_t)n * 2048 + c] = acc[i][jj][rg];
                }
    }
    grid.sync();

    // -------- persistent per-row CG state (block n = bid, j pair = 2t) -----
    const int n = bid;
    const int jj = 2 * t;
    float cix, ciy, cfx, cfy, cgx, cgy;
    float xx = 0.0f, xy = 0.0f, rx, ry, px, py;

    // ---------------- Phase G: gates + CG init ----------------
    {
        const float* z0 = zp + (size_t)n * 2048;
        const float* z1 = zp + (size_t)(NB + n) * 2048;
        #define LD2(pp) (*(const float2*)(pp))
        float2 zi = LD2(z0 + jj), zf = LD2(z0 + 512 + jj), zg = LD2(z0 + 1024 + jj), zo = LD2(z0 + 1536 + jj);
        float2 w1 = LD2(z1 + jj), w2 = LD2(z1 + 512 + jj), w3 = LD2(z1 + 1024 + jj), w4 = LD2(z1 + 1536 + jj);
        float2 b1 = LD2(bih + jj), b2 = LD2(bih + 512 + jj), b3 = LD2(bih + 1024 + jj), b4 = LD2(bih + 1536 + jj);
        float2 c1 = LD2(bhh + jj), c2 = LD2(bhh + 512 + jj), c3 = LD2(bhh + 1024 + jj), c4 = LD2(bhh + 1536 + jj);
        float2 cx2 = LD2(cx + (size_t)n * HH + jj);
        float hnx, hny, cnx, cny;
        gatecalc(zi.x + w1.x + b1.x + c1.x, zf.x + w2.x + b2.x + c2.x,
                 zg.x + w3.x + b3.x + c3.x, zo.x + w4.x + b4.x + c4.x, cx2.x,
                 hnx, cnx, cix, cfx, cgx);
        gatecalc(zi.y + w1.y + b1.y + c1.y, zf.y + w2.y + b2.y + c2.y,
                 zg.y + w3.y + b3.y + c3.y, zo.y + w4.y + b4.y + c4.y, cx2.y,
                 hny, cny, ciy, cfy, cgy);
        rx = px = cnx; ry = py = cny;
        float2 h2; h2.x = hnx; h2.y = hny;
        *(float2*)(out + (size_t)n * HH + jj) = h2;
        unsigned short* Ur = U + (size_t)n * K3H;
        ushort2v ui, uf, ug;
        ui[0] = f2bf(cix * px); ui[1] = f2bf(ciy * py);
        uf[0] = f2bf(cfx * px); uf[1] = f2bf(cfy * py);
        ug[0] = f2bf(cgx * px); ug[1] = f2bf(cgy * py);
        *(ushort2v*)(Ur + jj) = ui;
        *(ushort2v*)(Ur + 512 + jj) = uf;
        *(ushort2v*)(Ur + 1024 + jj) = ug;
        red[t] = cnx * cnx + cny * cny;
        __syncthreads();
        for (int s = 128; s > 0; s >>= 1) { if (t < s) red[t] += red[t + s]; __syncthreads(); }
        if (t == 0) sRho = red[0];
        __syncthreads();
    }
    grid.sync();

    // ---------------- CG loop ----------------
    for (int it = 0; it < CG_ITERS; ++it) {
        // Phase A: Vp[ks][n][j] partials, 192 blocks (4 n-tiles x 24 j-tiles x 2 K-slabs)
        if (bid < 192) {
            const int ks = bid & 1;
            const int tile = bid >> 1;
            const int a_n0 = (tile & 3) * 64;
            const int a_j0 = (tile >> 2) * 64;
            f32x4 acc[2][2] = {};
            for (int st = 0; st < 12; ++st) {
                const int kb = ks * 768 + st * 64;
                #pragma unroll
                for (int pp = 0; pp < 2; ++pp) {
                    const int row = pp * 32 + srow;
                    *(short8v*)&As[swz(row, scol8)] =
                        *(const short8v*)(U + (size_t)(a_n0 + row) * K3H + kb + scol8 * 8);
                    *(short8v*)&Bh[swz(row, scol8)] =
                        *(const short8v*)(Mhi + (size_t)(a_j0 + row) * K3H + kb + scol8 * 8);
                    *(short8v*)&Bl[swz(row, scol8)] =
                        *(const short8v*)(Mlo + (size_t)(a_j0 + row) * K3H + kb + scol8 * 8);
                }
                __syncthreads();
                #pragma unroll
                for (int ks2 = 0; ks2 < 2; ++ks2) {
                    short8v a[2], bh_[2], bl_[2];
                    #pragma unroll
                    for (int i = 0; i < 2; ++i) {
                        a[i]   = *(const short8v*)&As[swz(a_n0 >= 0 ? wm + i * 16 + fr : 0, ks2 * 4 + g)];
                        bh_[i] = *(const short8v*)&Bh[swz(wj + i * 16 + fr, ks2 * 4 + g)];
                        bl_[i] = *(const short8v*)&Bl[swz(wj + i * 16 + fr, ks2 * 4 + g)];
                    }
                    #pragma unroll
                    for (int i = 0; i < 2; ++i)
                        #pragma unroll
                        for (int q = 0; q < 2; ++q) {
                            acc[i][q] = __builtin_amdgcn_mfma_f32_16x16x32_bf16(a[i], bh_[q], acc[i][q], 0, 0, 0);
                            acc[i][q] = __builtin_amdgcn_mfma_f32_16x16x32_bf16(a[i], bl_[q], acc[i][q], 0, 0, 0);
                        }
                }
                __syncthreads();
            }
            float* Vs = Vp + (size_t)ks * (NB * K3H);
            #pragma unroll
            for (int i = 0; i < 2; ++i)
                #pragma unroll
                for (int q = 0; q < 2; ++q)
                    #pragma unroll
                    for (int rg = 0; rg < 4; ++rg) {
                        const int nn = a_n0 + wm + i * 16 + g * 4 + rg;
                        const int jx = a_j0 + wj + q * 16 + fr;
                        Vs[(size_t)nn * K3H + jx] = acc[i][q][rg];
                    }
        }
        grid.sync();

        // Phase B: per-row CG update (block n)
        {
            const float* V0 = Vp + (size_t)n * K3H;
            const float* V1 = Vp + (size_t)(NB + n) * K3H;
            float2 vi = LD2(V0 + jj),        vf = LD2(V0 + 512 + jj),  vg = LD2(V0 + 1024 + jj);
            float2 yi = LD2(V1 + jj),        yf = LD2(V1 + 512 + jj),  yg = LD2(V1 + 1024 + jj);
            const float Apx = px + cix * (vi.x + yi.x) + cfx * (vf.x + yf.x) + cgx * (vg.x + yg.x);
            const float Apy = py + ciy * (vi.y + yi.y) + cfy * (vf.y + yf.y) + cgy * (vg.y + yg.y);
            red[t] = px * Apx + py * Apy;
            __syncthreads();
            for (int s = 128; s > 0; s >>= 1) { if (t < s) red[t] += red[t + s]; __syncthreads(); }
            if (t == 0) sA = sRho / fmaxf(red[0], 1e-30f);
            __syncthreads();
            const float alpha = sA;
            xx += alpha * px; xy += alpha * py;
            rx -= alpha * Apx; ry -= alpha * Apy;
            red[t] = rx * rx + ry * ry;
            __syncthreads();
            for (int s = 128; s > 0; s >>= 1) { if (t < s) red[t] += red[t + s]; __syncthreads(); }
            if (t == 0) { const float rr = red[0]; sB2 = rr / fmaxf(sRho, 1e-30f); sRho = rr; }
            __syncthreads();
            const float beta = sB2;
            px = rx + beta * px; py = ry + beta * py;
            if (it < CG_ITERS - 1) {
                unsigned short* Ur = U + (size_t)n * K3H;
                ushort2v ui, uf2, ug2;
                ui[0]  = f2bf(cix * px); ui[1]  = f2bf(ciy * py);
                uf2[0] = f2bf(cfx * px); uf2[1] = f2bf(cfy * py);
                ug2[0] = f2bf(cgx * px); ug2[1] = f2bf(cgy * py);
                *(ushort2v*)(Ur + jj) = ui;
                *(ushort2v*)(Ur + 512 + jj) = uf2;
                *(ushort2v*)(Ur + 1024 + jj) = ug2;
            } else {
                float2 o2; o2.x = xx; o2.y = xy;
                *(float2*)(out + (size_t)NH + (size_t)n * HH + jj) = o2;
            }
        }
        grid.sync();
    }
}

// ---------------------------------------------------------------------------
extern "C" void kernel_launch(void* const* d_in, const int* in_sizes, int n_in,
                              void* d_out, int out_size, void* d_ws, size_t ws_size,
                              hipStream_t stream) {
    const float* x   = (const float*)d_in[0];
    const float* hx  = (const float*)d_in[1];
    const float* cx  = (const float*)d_in[2];
    const float* Wih = (const float*)d_in[3];
    const float* Whh = (const float*)d_in[4];
    const float* bih = (const float*)d_in[5];
    const float* bhh = (const float*)d_in[6];
    float* out = (float*)d_out;              // [h_new (131072) | prox_c (131072)]

    float* ws = (float*)d_ws;
    float* zp = ws;                                        // 2*256*2048 = 1,048,576 f
    float* Vp = zp + 2 * NB * 2048;                        // 2*256*1536 =   786,432 f
    unsigned short* Wihb = (unsigned short*)(Vp + 2 * NB * K3H);   // 1,048,576 us
    unsigned short* Whhb = Wihb + 2048 * 512;              // 1,048,576 us
    unsigned short* xb   = Whhb + 2048 * 512;              //   131,072 us
    unsigned short* hxb  = xb + NB * DD;                   //   131,072 us
    unsigned short* U    = hxb + NB * HH;                  //   393,216 us
    unsigned short* Mhi  = U + NB * K3H;                   // 2,359,296 us
    unsigned short* Mlo  = Mhi + (size_t)K3H * K3H;        // 2,359,296 us

    k_cvt<<<2304, 256, 0, stream>>>(Wih, Whh, x, hx, Wihb, Whhb, xb, hxb);
    k_gemm_m<<<576, 256, 0, stream>>>(Wihb, Mhi, Mlo);

    void* args[] = { (void*)&xb, (void*)&hxb, (void*)&Wihb, (void*)&Whhb,
                     (void*)&cx, (void*)&bih, (void*)&bhh,
                     (void*)&zp, (void*)&U, (void*)&Mhi, (void*)&Mlo,
                     (void*)&Vp, (void*)&out };
    hipLaunchCooperativeKernel(k_coop, dim3(256), dim3(256), args, 0, stream);
}

// Round 6
// 289.395 us; speedup vs baseline: 4.6564x; 4.6564x over previous
//
#include <hip/hip_runtime.h>
#include <math.h>

// Problem constants (reference: N=256, D=512, H=512, EPS=1.0)
#define NB   256
#define DD   512
#define HH   512
#define NH   (NB * HH)        // 131072
#define K3H  1536
#define CG_ITERS 14
#define VSLAB 4               // K-split of the V GEMM (1536 -> 4 x 384)

typedef __attribute__((ext_vector_type(8))) short   short8v;   // 8 x bf16 (4 VGPR)
typedef __attribute__((ext_vector_type(4))) float   f32x4;     // MFMA acc
typedef __attribute__((ext_vector_type(4))) unsigned short ushort4v;
typedef __attribute__((ext_vector_type(2))) unsigned short ushort2v;

__device__ __forceinline__ float sigmoidf_(float v) { return 1.0f / (1.0f + expf(-v)); }

// fp32 -> bf16 round-to-nearest-even
__device__ __forceinline__ unsigned short f2bf(float f) {
    union { float f; unsigned int u; } v; v.f = f;
    return (unsigned short)((v.u + 0x7FFFu + ((v.u >> 16) & 1u)) >> 16);
}
__device__ __forceinline__ float bf2f(unsigned short h) {
    union { unsigned int u; float f; } v; v.u = ((unsigned int)h) << 16;
    return v.f;
}

// Swizzled LDS index (in shorts) for 64-col bf16 rows, 16B slots: <=2-way (free).
__device__ __forceinline__ int swz(int row, int col8) {
    return row * 64 + ((col8 ^ (row & 7)) << 3);
}

// ---------------------------------------------------------------------------
// Prep A: fp32 -> bf16 for Wih(2048x512), Whh(2048x512), x, hx.  2304 blocks.
// ---------------------------------------------------------------------------
__global__ __launch_bounds__(256) void k_cvt(
    const float* __restrict__ Wih, const float* __restrict__ Whh,
    const float* __restrict__ x, const float* __restrict__ hx,
    unsigned short* __restrict__ Wihb, unsigned short* __restrict__ Whhb,
    unsigned short* __restrict__ xb, unsigned short* __restrict__ hxb)
{
    const int idx = (blockIdx.x * 256 + threadIdx.x) * 4;   // 2,359,296 total elems
    const float* src; unsigned short* dst; int off;
    if      (idx < 1048576) { src = Wih; dst = Wihb; off = idx; }
    else if (idx < 2097152) { src = Whh; dst = Whhb; off = idx - 1048576; }
    else if (idx < 2228224) { src = x;   dst = xb;   off = idx - 2097152; }
    else                    { src = hx;  dst = hxb;  off = idx - 2228224; }
    float4 v = *(const float4*)(src + off);
    ushort4v o;
    o[0] = f2bf(v.x); o[1] = f2bf(v.y); o[2] = f2bf(v.z); o[3] = f2bf(v.w);
    *(ushort4v*)(dst + off) = o;
}

// ---------------------------------------------------------------------------
// Prep B (MFMA): M = W13 @ W13^T  (1536x1536), W13 = first 1536 rows of Wih.
// Stored as bf16 hi/lo pair (fp32-accurate operator). Grid 576 blocks.
// ---------------------------------------------------------------------------
__global__ __launch_bounds__(256) void k_gemm_m(
    const unsigned short* __restrict__ Wihb,
    unsigned short* __restrict__ Mhi, unsigned short* __restrict__ Mlo)
{
    __shared__ unsigned short As[4096];
    __shared__ unsigned short Bs[4096];
    const int r0 = (blockIdx.x / 24) * 64;
    const int c0 = (blockIdx.x % 24) * 64;
    const int t = threadIdx.x;
    const int w = t >> 6, lane = t & 63;
    const int wm = (w >> 1) * 32, wc = (w & 1) * 32;
    const int fr = lane & 15, g = lane >> 4;
    const int srow = t >> 3, scol8 = t & 7;
    f32x4 acc[2][2] = {};
    for (int st = 0; st < 8; ++st) {
        const int kk = st * 64;
        #pragma unroll
        for (int pp = 0; pp < 2; ++pp) {
            const int row = pp * 32 + srow;
            *(short8v*)&As[swz(row, scol8)] =
                *(const short8v*)(Wihb + (size_t)(r0 + row) * DD + kk + scol8 * 8);
            *(short8v*)&Bs[swz(row, scol8)] =
                *(const short8v*)(Wihb + (size_t)(c0 + row) * DD + kk + scol8 * 8);
        }
        __syncthreads();
        #pragma unroll
        for (int ks2 = 0; ks2 < 2; ++ks2) {
            short8v a[2], b[2];
            #pragma unroll
            for (int i = 0; i < 2; ++i) {
                a[i] = *(const short8v*)&As[swz(wm + i * 16 + fr, ks2 * 4 + g)];
                b[i] = *(const short8v*)&Bs[swz(wc + i * 16 + fr, ks2 * 4 + g)];
            }
            #pragma unroll
            for (int i = 0; i < 2; ++i)
                #pragma unroll
                for (int jj = 0; jj < 2; ++jj)
                    acc[i][jj] = __builtin_amdgcn_mfma_f32_16x16x32_bf16(a[i], b[jj], acc[i][jj], 0, 0, 0);
        }
        __syncthreads();
    }
    #pragma unroll
    for (int i = 0; i < 2; ++i)
        #pragma unroll
        for (int jj = 0; jj < 2; ++jj)
            #pragma unroll
            for (int rg = 0; rg < 4; ++rg) {
                const int r = r0 + wm + i * 16 + g * 4 + rg;
                const int c = c0 + wc + jj * 16 + fr;
                const float v = acc[i][jj][rg];
                const unsigned short h = f2bf(v);
                Mhi[(size_t)r * K3H + c] = h;
                Mlo[(size_t)r * K3H + c] = f2bf(v - bf2f(h));
            }
}

// ---------------------------------------------------------------------------
// Kernel Z (MFMA): zp[sl][n][c] = partial of [x|hx] @ [Wih|Whh]^T
// Tile 64n x 64c, K=1024 split 2. Grid (32,4,2)=256 blocks.
// ---------------------------------------------------------------------------
__global__ __launch_bounds__(256) void k_gemm_z(
    const unsigned short* __restrict__ xb, const unsigned short* __restrict__ hxb,
    const unsigned short* __restrict__ Wihb, const unsigned short* __restrict__ Whhb,
    float* __restrict__ zp)
{
    __shared__ unsigned short As[4096];
    __shared__ unsigned short Bs[4096];
    const int j0 = blockIdx.x * 64;
    const int n0 = blockIdx.y * 64;
    const int sl = blockIdx.z;
    const int t = threadIdx.x;
    const int w = t >> 6, lane = t & 63;
    const int wm = (w >> 1) * 32, wjn = (w & 1) * 32;
    const int fr = lane & 15, g = lane >> 4;
    const int srow = t >> 3, scol8 = t & 7;
    const unsigned short* Asrc = sl ? hxb : xb;
    const unsigned short* Bsrc = sl ? Whhb : Wihb;
    f32x4 acc[2][2] = {};
    for (int st = 0; st < 8; ++st) {
        const int kk = st * 64;
        #pragma unroll
        for (int pp = 0; pp < 2; ++pp) {
            const int row = pp * 32 + srow;
            *(short8v*)&As[swz(row, scol8)] =
                *(const short8v*)(Asrc + (size_t)(n0 + row) * DD + kk + scol8 * 8);
            *(short8v*)&Bs[swz(row, scol8)] =
                *(const short8v*)(Bsrc + (size_t)(j0 + row) * DD + kk + scol8 * 8);
        }
        __syncthreads();
        #pragma unroll
        for (int ks2 = 0; ks2 < 2; ++ks2) {
            short8v a[2], b[2];
            #pragma unroll
            for (int i = 0; i < 2; ++i) {
                a[i] = *(const short8v*)&As[swz(wm  + i * 16 + fr, ks2 * 4 + g)];
                b[i] = *(const short8v*)&Bs[swz(wjn + i * 16 + fr, ks2 * 4 + g)];
            }
            #pragma unroll
            for (int i = 0; i < 2; ++i)
                #pragma unroll
                for (int jj = 0; jj < 2; ++jj)
                    acc[i][jj] = __builtin_amdgcn_mfma_f32_16x16x32_bf16(a[i], b[jj], acc[i][jj], 0, 0, 0);
        }
        __syncthreads();
    }
    float* Z = zp + (size_t)sl * NB * 2048;
    #pragma unroll
    for (int i = 0; i < 2; ++i)
        #pragma unroll
        for (int jj = 0; jj < 2; ++jj)
            #pragma unroll
            for (int rg = 0; rg < 4; ++rg) {
                const int n = n0 + wm + i * 16 + g * 4 + rg;
                const int c = j0 + wjn + jj * 16 + fr;
                Z[(size_t)n * 2048 + c] = acc[i][jj][rg];
            }
}

// ---------------------------------------------------------------------------
// Gates + CG init. Block n, thread handles j = 2t, 2t+1.
// Writes h_new, Ci/Cf/Cg, xsol=0, r=p=c_new, rho, U = C .* p (bf16).
// ---------------------------------------------------------------------------
__global__ __launch_bounds__(256) void k_gates_init(
    const float* __restrict__ zp, const float* __restrict__ cx,
    const float* __restrict__ bih, const float* __restrict__ bhh,
    float* __restrict__ hOut,
    float* __restrict__ Ci, float* __restrict__ Cf, float* __restrict__ Cg,
    float* __restrict__ xsol, float* __restrict__ r, float* __restrict__ p,
    unsigned short* __restrict__ U, float* __restrict__ rho)
{
    __shared__ float red[256];
    const int n = blockIdx.x, t = threadIdx.x;
    const int jj = 2 * t;
    const float* z0 = zp + (size_t)n * 2048;
    const float* z1 = zp + (size_t)(NB + n) * 2048;
    float part = 0.0f;
    float2 cn2, ci2, cf2, cg2;
    {
        #pragma unroll
        for (int e = 0; e < 2; ++e) {
            const int h = jj + e;
            const float zi = z0[h]        + z1[h]        + bih[h]        + bhh[h];
            const float zf = z0[512 + h]  + z1[512 + h]  + bih[512 + h]  + bhh[512 + h];
            const float zg = z0[1024 + h] + z1[1024 + h] + bih[1024 + h] + bhh[1024 + h];
            const float zo = z0[1536 + h] + z1[1536 + h] + bih[1536 + h] + bhh[1536 + h];
            const float iv = sigmoidf_(zi), fv = sigmoidf_(zf);
            const float gv = tanhf(zg),     ov = sigmoidf_(zo);
            const float cxv = cx[(size_t)n * HH + h];
            const float cn = fv * cxv + iv * gv;
            hOut[(size_t)n * HH + h] = ov * tanhf(cn);
            ((float*)&cn2)[e] = cn;
            ((float*)&ci2)[e] = iv * (1.0f - iv) * gv;
            ((float*)&cf2)[e] = fv * (1.0f - fv) * cxv;
            ((float*)&cg2)[e] = (1.0f - gv * gv) * iv;
            part += cn * cn;
        }
    }
    const size_t base = (size_t)n * HH + jj;
    *(float2*)(Ci + base) = ci2;
    *(float2*)(Cf + base) = cf2;
    *(float2*)(Cg + base) = cg2;
    float2 zero2; zero2.x = 0.0f; zero2.y = 0.0f;
    *(float2*)(xsol + base) = zero2;
    *(float2*)(r + base) = cn2;
    *(float2*)(p + base) = cn2;
    unsigned short* Ur = U + (size_t)n * K3H;
    ushort2v ui, uf, ug;
    ui[0] = f2bf(ci2.x * cn2.x); ui[1] = f2bf(ci2.y * cn2.y);
    uf[0] = f2bf(cf2.x * cn2.x); uf[1] = f2bf(cf2.y * cn2.y);
    ug[0] = f2bf(cg2.x * cn2.x); ug[1] = f2bf(cg2.y * cn2.y);
    *(ushort2v*)(Ur + jj)        = ui;
    *(ushort2v*)(Ur + 512 + jj)  = uf;
    *(ushort2v*)(Ur + 1024 + jj) = ug;
    red[t] = part; __syncthreads();
    for (int s = 128; s > 0; s >>= 1) { if (t < s) red[t] += red[t + s]; __syncthreads(); }
    if (t == 0) rho[n] = red[0];
}

// ---------------------------------------------------------------------------
// In-loop GEMM: Vp[sl][n][c] = partial of U @ (Mhi+Mlo)^T  (M symmetric).
// K=1536 split into VSLAB=4 slabs of 384 (6 stages of 64).
// Grid (24 c-tiles, 4 n-tiles, 4 slabs) = 384 blocks.
// ---------------------------------------------------------------------------
__global__ __launch_bounds__(256) void k_gemm_v(
    const unsigned short* __restrict__ U,
    const unsigned short* __restrict__ Mhi, const unsigned short* __restrict__ Mlo,
    float* __restrict__ Vp)
{
    __shared__ unsigned short As[4096];
    __shared__ unsigned short Bh[4096];
    __shared__ unsigned short Bl[4096];
    const int c0 = blockIdx.x * 64;
    const int n0 = blockIdx.y * 64;
    const int sl = blockIdx.z;
    const int t = threadIdx.x;
    const int w = t >> 6, lane = t & 63;
    const int wm = (w >> 1) * 32, wc = (w & 1) * 32;
    const int fr = lane & 15, g = lane >> 4;
    const int srow = t >> 3, scol8 = t & 7;
    f32x4 acc[2][2] = {};
    for (int st = 0; st < 6; ++st) {
        const int kb = sl * 384 + st * 64;
        #pragma unroll
        for (int pp = 0; pp < 2; ++pp) {
            const int row = pp * 32 + srow;
            *(short8v*)&As[swz(row, scol8)] =
                *(const short8v*)(U + (size_t)(n0 + row) * K3H + kb + scol8 * 8);
            *(short8v*)&Bh[swz(row, scol8)] =
                *(const short8v*)(Mhi + (size_t)(c0 + row) * K3H + kb + scol8 * 8);
            *(short8v*)&Bl[swz(row, scol8)] =
                *(const short8v*)(Mlo + (size_t)(c0 + row) * K3H + kb + scol8 * 8);
        }
        __syncthreads();
        #pragma unroll
        for (int ks2 = 0; ks2 < 2; ++ks2) {
            short8v a[2], bh_[2], bl_[2];
            #pragma unroll
            for (int i = 0; i < 2; ++i) {
                a[i]   = *(const short8v*)&As[swz(wm + i * 16 + fr, ks2 * 4 + g)];
                bh_[i] = *(const short8v*)&Bh[swz(wc + i * 16 + fr, ks2 * 4 + g)];
                bl_[i] = *(const short8v*)&Bl[swz(wc + i * 16 + fr, ks2 * 4 + g)];
            }
            #pragma unroll
            for (int i = 0; i < 2; ++i)
                #pragma unroll
                for (int q = 0; q < 2; ++q) {
                    acc[i][q] = __builtin_amdgcn_mfma_f32_16x16x32_bf16(a[i], bh_[q], acc[i][q], 0, 0, 0);
                    acc[i][q] = __builtin_amdgcn_mfma_f32_16x16x32_bf16(a[i], bl_[q], acc[i][q], 0, 0, 0);
                }
        }
        __syncthreads();
    }
    float* Vs = Vp + (size_t)sl * (NB * K3H);
    #pragma unroll
    for (int i = 0; i < 2; ++i)
        #pragma unroll
        for (int q = 0; q < 2; ++q)
            #pragma unroll
            for (int rg = 0; rg < 4; ++rg) {
                const int nn = n0 + wm + i * 16 + g * 4 + rg;
                const int cc = c0 + wc + q * 16 + fr;
                Vs[(size_t)nn * K3H + cc] = acc[i][q][rg];
            }
}

// ---------------------------------------------------------------------------
// CG vector step. Block n, thread handles j = 2t, 2t+1.
// Ap = p + sum_a Ca .* (sum_sl Vp[sl][n][a*512+j]); dots block-local;
// updates xsol, r, p; writes next U (bf16); writes prox out on last iter.
// ---------------------------------------------------------------------------
__global__ __launch_bounds__(256) void k_cg_update(
    float* __restrict__ xsol, float* __restrict__ r, float* __restrict__ p,
    const float* __restrict__ Ci, const float* __restrict__ Cf, const float* __restrict__ Cg,
    const float* __restrict__ Vp, float* __restrict__ rho,
    unsigned short* __restrict__ U, float* __restrict__ outProx, int writeOut)
{
    __shared__ float red[256];
    __shared__ float sA, sB2;
    const int n = blockIdx.x, t = threadIdx.x;
    const int jj = 2 * t;
    const size_t base = (size_t)n * HH + jj;
    float2 pv = *(float2*)(p + base);
    float2 ci2 = *(const float2*)(Ci + base);
    float2 cf2 = *(const float2*)(Cf + base);
    float2 cg2 = *(const float2*)(Cg + base);
    float2 vi = {0.f, 0.f}, vf = {0.f, 0.f}, vg = {0.f, 0.f};
    #pragma unroll
    for (int s = 0; s < VSLAB; ++s) {
        const float* Vr = Vp + (size_t)s * (NB * K3H) + (size_t)n * K3H;
        float2 a = *(const float2*)(Vr + jj);
        float2 b = *(const float2*)(Vr + 512 + jj);
        float2 c = *(const float2*)(Vr + 1024 + jj);
        vi.x += a.x; vi.y += a.y;
        vf.x += b.x; vf.y += b.y;
        vg.x += c.x; vg.y += c.y;
    }
    const float Apx = pv.x + ci2.x * vi.x + cf2.x * vf.x + cg2.x * vg.x;
    const float Apy = pv.y + ci2.y * vi.y + cf2.y * vf.y + cg2.y * vg.y;
    red[t] = pv.x * Apx + pv.y * Apy;
    __syncthreads();
    for (int s = 128; s > 0; s >>= 1) { if (t < s) red[t] += red[t + s]; __syncthreads(); }
    if (t == 0) sA = rho[n] / fmaxf(red[0], 1e-30f);
    __syncthreads();
    const float alpha = sA;
    float2 xv = *(float2*)(xsol + base);
    xv.x += alpha * pv.x; xv.y += alpha * pv.y;
    *(float2*)(xsol + base) = xv;
    float2 rv = *(float2*)(r + base);
    rv.x -= alpha * Apx; rv.y -= alpha * Apy;
    *(float2*)(r + base) = rv;
    red[t] = rv.x * rv.x + rv.y * rv.y;
    __syncthreads();
    for (int s = 128; s > 0; s >>= 1) { if (t < s) red[t] += red[t + s]; __syncthreads(); }
    if (t == 0) { const float rr = red[0]; sB2 = rr / fmaxf(rho[n], 1e-30f); rho[n] = rr; }
    __syncthreads();
    const float beta = sB2;
    pv.x = rv.x + beta * pv.x; pv.y = rv.y + beta * pv.y;
    *(float2*)(p + base) = pv;
    unsigned short* Ur = U + (size_t)n * K3H;
    ushort2v ui, uf2, ug2;
    ui[0]  = f2bf(ci2.x * pv.x); ui[1]  = f2bf(ci2.y * pv.y);
    uf2[0] = f2bf(cf2.x * pv.x); uf2[1] = f2bf(cf2.y * pv.y);
    ug2[0] = f2bf(cg2.x * pv.x); ug2[1] = f2bf(cg2.y * pv.y);
    *(ushort2v*)(Ur + jj)        = ui;
    *(ushort2v*)(Ur + 512 + jj)  = uf2;
    *(ushort2v*)(Ur + 1024 + jj) = ug2;
    if (writeOut) {
        float2 o2; o2.x = xv.x; o2.y = xv.y;
        *(float2*)(outProx + base) = o2;
    }
}

// ---------------------------------------------------------------------------
extern "C" void kernel_launch(void* const* d_in, const int* in_sizes, int n_in,
                              void* d_out, int out_size, void* d_ws, size_t ws_size,
                              hipStream_t stream) {
    const float* x   = (const float*)d_in[0];
    const float* hx  = (const float*)d_in[1];
    const float* cx  = (const float*)d_in[2];
    const float* Wih = (const float*)d_in[3];
    const float* Whh = (const float*)d_in[4];
    const float* bih = (const float*)d_in[5];
    const float* bhh = (const float*)d_in[6];
    float* out = (float*)d_out;              // [h_new (131072) | prox_c (131072)]

    float* ws = (float*)d_ws;
    float* zp   = ws;                                  // 2*256*2048 = 1,048,576 f
    float* Ci   = zp + 2 * NB * 2048;
    float* Cf   = Ci + NH;
    float* Cg   = Cf + NH;
    float* xsol = Cg + NH;
    float* r    = xsol + NH;
    float* p    = r + NH;
    float* Vp   = p + NH;                              // VSLAB * 256*1536 f
    float* rho  = Vp + (size_t)VSLAB * NB * K3H;       // 256 f
    unsigned short* Wihb = (unsigned short*)(rho + 256);   // 1,048,576 us
    unsigned short* Whhb = Wihb + 2048 * 512;              // 1,048,576 us
    unsigned short* xb   = Whhb + 2048 * 512;              //   131,072 us
    unsigned short* hxb  = xb + NB * DD;                   //   131,072 us
    unsigned short* U    = hxb + NB * HH;                  //   393,216 us
    unsigned short* Mhi  = U + NB * K3H;                   // 2,359,296 us
    unsigned short* Mlo  = Mhi + (size_t)K3H * K3H;        // 2,359,296 us

    k_cvt<<<2304, 256, 0, stream>>>(Wih, Whh, x, hx, Wihb, Whhb, xb, hxb);
    k_gemm_m<<<576, 256, 0, stream>>>(Wihb, Mhi, Mlo);
    k_gemm_z<<<dim3(32, 4, 2), 256, 0, stream>>>(xb, hxb, Wihb, Whhb, zp);
    k_gates_init<<<NB, 256, 0, stream>>>(zp, cx, bih, bhh, out,
                                         Ci, Cf, Cg, xsol, r, p, U, rho);

    for (int it = 0; it < CG_ITERS; ++it) {
        k_gemm_v<<<dim3(24, 4, VSLAB), 256, 0, stream>>>(U, Mhi, Mlo, Vp);
        k_cg_update<<<NB, 256, 0, stream>>>(xsol, r, p, Ci, Cf, Cg, Vp, rho, U,
                                            out + NH, (it == CG_ITERS - 1) ? 1 : 0);
    }
}

// Round 7
// 271.360 us; speedup vs baseline: 4.9658x; 1.0665x over previous
//
#include <hip/hip_runtime.h>
#include <math.h>

// Problem constants (reference: N=256, D=512, H=512, EPS=1.0)
#define NB   256
#define DD   512
#define HH   512
#define NH   (NB * HH)        // 131072
#define K3H  1536
#define CG_ITERS 12
#define VSLAB 8               // K-split of the V GEMM (1536 -> 8 x 192)

typedef __attribute__((ext_vector_type(8))) short   short8v;   // 8 x bf16 (4 VGPR)
typedef __attribute__((ext_vector_type(4))) float   f32x4;     // MFMA acc
typedef __attribute__((ext_vector_type(4))) unsigned short ushort4v;
typedef __attribute__((ext_vector_type(2))) unsigned short ushort2v;

__device__ __forceinline__ float sigmoidf_(float v) { return 1.0f / (1.0f + expf(-v)); }

// fp32 -> bf16 round-to-nearest-even
__device__ __forceinline__ unsigned short f2bf(float f) {
    union { float f; unsigned int u; } v; v.f = f;
    return (unsigned short)((v.u + 0x7FFFu + ((v.u >> 16) & 1u)) >> 16);
}

// Swizzled LDS index (in shorts) for 64-col bf16 rows, 16B slots: <=2-way (free).
__device__ __forceinline__ int swz(int row, int col8) {
    return row * 64 + ((col8 ^ (row & 7)) << 3);
}

// ---------------------------------------------------------------------------
// Prep A: fp32 -> bf16 for Wih(2048x512), Whh(2048x512), x, hx.  2304 blocks.
// ---------------------------------------------------------------------------
__global__ __launch_bounds__(256) void k_cvt(
    const float* __restrict__ Wih, const float* __restrict__ Whh,
    const float* __restrict__ x, const float* __restrict__ hx,
    unsigned short* __restrict__ Wihb, unsigned short* __restrict__ Whhb,
    unsigned short* __restrict__ xb, unsigned short* __restrict__ hxb)
{
    const int idx = (blockIdx.x * 256 + threadIdx.x) * 4;   // 2,359,296 total elems
    const float* src; unsigned short* dst; int off;
    if      (idx < 1048576) { src = Wih; dst = Wihb; off = idx; }
    else if (idx < 2097152) { src = Whh; dst = Whhb; off = idx - 1048576; }
    else if (idx < 2228224) { src = x;   dst = xb;   off = idx - 2097152; }
    else                    { src = hx;  dst = hxb;  off = idx - 2228224; }
    float4 v = *(const float4*)(src + off);
    ushort4v o;
    o[0] = f2bf(v.x); o[1] = f2bf(v.y); o[2] = f2bf(v.z); o[3] = f2bf(v.w);
    *(ushort4v*)(dst + off) = o;
}

// ---------------------------------------------------------------------------
// Prep B (MFMA): M = W13 @ W13^T  (1536x1536), bf16. Grid 576 blocks.
// ---------------------------------------------------------------------------
__global__ __launch_bounds__(256) void k_gemm_m(
    const unsigned short* __restrict__ Wihb, unsigned short* __restrict__ Mb)
{
    __shared__ unsigned short As[4096];
    __shared__ unsigned short Bs[4096];
    const int r0 = (blockIdx.x / 24) * 64;
    const int c0 = (blockIdx.x % 24) * 64;
    const int t = threadIdx.x;
    const int w = t >> 6, lane = t & 63;
    const int wm = (w >> 1) * 32, wc = (w & 1) * 32;
    const int fr = lane & 15, g = lane >> 4;
    const int srow = t >> 3, scol8 = t & 7;
    f32x4 acc[2][2] = {};
    for (int st = 0; st < 8; ++st) {
        const int kk = st * 64;
        #pragma unroll
        for (int pp = 0; pp < 2; ++pp) {
            const int row = pp * 32 + srow;
            *(short8v*)&As[swz(row, scol8)] =
                *(const short8v*)(Wihb + (size_t)(r0 + row) * DD + kk + scol8 * 8);
            *(short8v*)&Bs[swz(row, scol8)] =
                *(const short8v*)(Wihb + (size_t)(c0 + row) * DD + kk + scol8 * 8);
        }
        __syncthreads();
        #pragma unroll
        for (int ks2 = 0; ks2 < 2; ++ks2) {
            short8v a[2], b[2];
            #pragma unroll
            for (int i = 0; i < 2; ++i) {
                a[i] = *(const short8v*)&As[swz(wm + i * 16 + fr, ks2 * 4 + g)];
                b[i] = *(const short8v*)&Bs[swz(wc + i * 16 + fr, ks2 * 4 + g)];
            }
            #pragma unroll
            for (int i = 0; i < 2; ++i)
                #pragma unroll
                for (int jj = 0; jj < 2; ++jj)
                    acc[i][jj] = __builtin_amdgcn_mfma_f32_16x16x32_bf16(a[i], b[jj], acc[i][jj], 0, 0, 0);
        }
        __syncthreads();
    }
    #pragma unroll
    for (int i = 0; i < 2; ++i)
        #pragma unroll
        for (int jj = 0; jj < 2; ++jj)
            #pragma unroll
            for (int rg = 0; rg < 4; ++rg) {
                const int r = r0 + wm + i * 16 + g * 4 + rg;
                const int c = c0 + wc + jj * 16 + fr;
                Mb[(size_t)r * K3H + c] = f2bf(acc[i][jj][rg]);
            }
}

// ---------------------------------------------------------------------------
// Kernel Z (MFMA): zp[sl][n][c] = partial of [x|hx] @ [Wih|Whh]^T
// Tile 64n x 64c, K=1024 split 2. Grid (32,4,2)=256 blocks.
// ---------------------------------------------------------------------------
__global__ __launch_bounds__(256) void k_gemm_z(
    const unsigned short* __restrict__ xb, const unsigned short* __restrict__ hxb,
    const unsigned short* __restrict__ Wihb, const unsigned short* __restrict__ Whhb,
    float* __restrict__ zp)
{
    __shared__ unsigned short As[4096];
    __shared__ unsigned short Bs[4096];
    const int j0 = blockIdx.x * 64;
    const int n0 = blockIdx.y * 64;
    const int sl = blockIdx.z;
    const int t = threadIdx.x;
    const int w = t >> 6, lane = t & 63;
    const int wm = (w >> 1) * 32, wjn = (w & 1) * 32;
    const int fr = lane & 15, g = lane >> 4;
    const int srow = t >> 3, scol8 = t & 7;
    const unsigned short* Asrc = sl ? hxb : xb;
    const unsigned short* Bsrc = sl ? Whhb : Wihb;
    f32x4 acc[2][2] = {};
    for (int st = 0; st < 8; ++st) {
        const int kk = st * 64;
        #pragma unroll
        for (int pp = 0; pp < 2; ++pp) {
            const int row = pp * 32 + srow;
            *(short8v*)&As[swz(row, scol8)] =
                *(const short8v*)(Asrc + (size_t)(n0 + row) * DD + kk + scol8 * 8);
            *(short8v*)&Bs[swz(row, scol8)] =
                *(const short8v*)(Bsrc + (size_t)(j0 + row) * DD + kk + scol8 * 8);
        }
        __syncthreads();
        #pragma unroll
        for (int ks2 = 0; ks2 < 2; ++ks2) {
            short8v a[2], b[2];
            #pragma unroll
            for (int i = 0; i < 2; ++i) {
                a[i] = *(const short8v*)&As[swz(wm  + i * 16 + fr, ks2 * 4 + g)];
                b[i] = *(const short8v*)&Bs[swz(wjn + i * 16 + fr, ks2 * 4 + g)];
            }
            #pragma unroll
            for (int i = 0; i < 2; ++i)
                #pragma unroll
                for (int jj = 0; jj < 2; ++jj)
                    acc[i][jj] = __builtin_amdgcn_mfma_f32_16x16x32_bf16(a[i], b[jj], acc[i][jj], 0, 0, 0);
        }
        __syncthreads();
    }
    float* Z = zp + (size_t)sl * NB * 2048;
    #pragma unroll
    for (int i = 0; i < 2; ++i)
        #pragma unroll
        for (int jj = 0; jj < 2; ++jj)
            #pragma unroll
            for (int rg = 0; rg < 4; ++rg) {
                const int n = n0 + wm + i * 16 + g * 4 + rg;
                const int c = j0 + wjn + jj * 16 + fr;
                Z[(size_t)n * 2048 + c] = acc[i][jj][rg];
            }
}

// ---------------------------------------------------------------------------
// Gates + CG init. Block n, thread handles j = 2t, 2t+1.
// Writes h_new, Ci/Cf/Cg, xsol=0, r=p=c_new, rho, U = C .* p (bf16).
// ---------------------------------------------------------------------------
__global__ __launch_bounds__(256) void k_gates_init(
    const float* __restrict__ zp, const float* __restrict__ cx,
    const float* __restrict__ bih, const float* __restrict__ bhh,
    float* __restrict__ hOut,
    float* __restrict__ Ci, float* __restrict__ Cf, float* __restrict__ Cg,
    float* __restrict__ xsol, float* __restrict__ r, float* __restrict__ p,
    unsigned short* __restrict__ U, float* __restrict__ rho)
{
    __shared__ float red[256];
    const int n = blockIdx.x, t = threadIdx.x;
    const int jj = 2 * t;
    const float* z0 = zp + (size_t)n * 2048;
    const float* z1 = zp + (size_t)(NB + n) * 2048;
    float part = 0.0f;
    float2 cn2, ci2, cf2, cg2;
    {
        #pragma unroll
        for (int e = 0; e < 2; ++e) {
            const int h = jj + e;
            const float zi = z0[h]        + z1[h]        + bih[h]        + bhh[h];
            const float zf = z0[512 + h]  + z1[512 + h]  + bih[512 + h]  + bhh[512 + h];
            const float zg = z0[1024 + h] + z1[1024 + h] + bih[1024 + h] + bhh[1024 + h];
            const float zo = z0[1536 + h] + z1[1536 + h] + bih[1536 + h] + bhh[1536 + h];
            const float iv = sigmoidf_(zi), fv = sigmoidf_(zf);
            const float gv = tanhf(zg),     ov = sigmoidf_(zo);
            const float cxv = cx[(size_t)n * HH + h];
            const float cn = fv * cxv + iv * gv;
            hOut[(size_t)n * HH + h] = ov * tanhf(cn);
            ((float*)&cn2)[e] = cn;
            ((float*)&ci2)[e] = iv * (1.0f - iv) * gv;
            ((float*)&cf2)[e] = fv * (1.0f - fv) * cxv;
            ((float*)&cg2)[e] = (1.0f - gv * gv) * iv;
            part += cn * cn;
        }
    }
    const size_t base = (size_t)n * HH + jj;
    *(float2*)(Ci + base) = ci2;
    *(float2*)(Cf + base) = cf2;
    *(float2*)(Cg + base) = cg2;
    float2 zero2; zero2.x = 0.0f; zero2.y = 0.0f;
    *(float2*)(xsol + base) = zero2;
    *(float2*)(r + base) = cn2;
    *(float2*)(p + base) = cn2;
    unsigned short* Ur = U + (size_t)n * K3H;
    ushort2v ui, uf, ug;
    ui[0] = f2bf(ci2.x * cn2.x); ui[1] = f2bf(ci2.y * cn2.y);
    uf[0] = f2bf(cf2.x * cn2.x); uf[1] = f2bf(cf2.y * cn2.y);
    ug[0] = f2bf(cg2.x * cn2.x); ug[1] = f2bf(cg2.y * cn2.y);
    *(ushort2v*)(Ur + jj)        = ui;
    *(ushort2v*)(Ur + 512 + jj)  = uf;
    *(ushort2v*)(Ur + 1024 + jj) = ug;
    red[t] = part; __syncthreads();
    for (int s = 128; s > 0; s >>= 1) { if (t < s) red[t] += red[t + s]; __syncthreads(); }
    if (t == 0) rho[n] = red[0];
}

// ---------------------------------------------------------------------------
// In-loop GEMM: Vp[sl][n][c] = partial of U @ Mb^T  (M symmetric, bf16).
// K=1536 split into VSLAB=8 slabs of 192 (3 stages of 64).
// Grid (24 c-tiles, 4 n-tiles, 8 slabs) = 768 blocks.
// ---------------------------------------------------------------------------
__global__ __launch_bounds__(256) void k_gemm_v(
    const unsigned short* __restrict__ U,
    const unsigned short* __restrict__ Mb,
    float* __restrict__ Vp)
{
    __shared__ unsigned short As[4096];
    __shared__ unsigned short Bs[4096];
    const int c0 = blockIdx.x * 64;
    const int n0 = blockIdx.y * 64;
    const int sl = blockIdx.z;
    const int t = threadIdx.x;
    const int w = t >> 6, lane = t & 63;
    const int wm = (w >> 1) * 32, wc = (w & 1) * 32;
    const int fr = lane & 15, g = lane >> 4;
    const int srow = t >> 3, scol8 = t & 7;
    f32x4 acc[2][2] = {};
    for (int st = 0; st < 3; ++st) {
        const int kb = sl * 192 + st * 64;
        #pragma unroll
        for (int pp = 0; pp < 2; ++pp) {
            const int row = pp * 32 + srow;
            *(short8v*)&As[swz(row, scol8)] =
                *(const short8v*)(U + (size_t)(n0 + row) * K3H + kb + scol8 * 8);
            *(short8v*)&Bs[swz(row, scol8)] =
                *(const short8v*)(Mb + (size_t)(c0 + row) * K3H + kb + scol8 * 8);
        }
        __syncthreads();
        #pragma unroll
        for (int ks2 = 0; ks2 < 2; ++ks2) {
            short8v a[2], b[2];
            #pragma unroll
            for (int i = 0; i < 2; ++i) {
                a[i] = *(const short8v*)&As[swz(wm + i * 16 + fr, ks2 * 4 + g)];
                b[i] = *(const short8v*)&Bs[swz(wc + i * 16 + fr, ks2 * 4 + g)];
            }
            #pragma unroll
            for (int i = 0; i < 2; ++i)
                #pragma unroll
                for (int q = 0; q < 2; ++q)
                    acc[i][q] = __builtin_amdgcn_mfma_f32_16x16x32_bf16(a[i], b[q], acc[i][q], 0, 0, 0);
        }
        __syncthreads();
    }
    float* Vs = Vp + (size_t)sl * (NB * K3H);
    #pragma unroll
    for (int i = 0; i < 2; ++i)
        #pragma unroll
        for (int q = 0; q < 2; ++q)
            #pragma unroll
            for (int rg = 0; rg < 4; ++rg) {
                const int nn = n0 + wm + i * 16 + g * 4 + rg;
                const int cc = c0 + wc + q * 16 + fr;
                Vs[(size_t)nn * K3H + cc] = acc[i][q][rg];
            }
}

// ---------------------------------------------------------------------------
// CG vector step. Block n, thread handles j = 2t, 2t+1.
// Ap = p + sum_a Ca .* (sum_sl Vp[sl][n][a*512+j]); dots block-local;
// updates xsol, r, p; writes next U (bf16); writes prox out on last iter.
// ---------------------------------------------------------------------------
__global__ __launch_bounds__(256) void k_cg_update(
    float* __restrict__ xsol, float* __restrict__ r, float* __restrict__ p,
    const float* __restrict__ Ci, const float* __restrict__ Cf, const float* __restrict__ Cg,
    const float* __restrict__ Vp, float* __restrict__ rho,
    unsigned short* __restrict__ U, float* __restrict__ outProx, int writeOut)
{
    __shared__ float red[256];
    __shared__ float sA, sB2;
    const int n = blockIdx.x, t = threadIdx.x;
    const int jj = 2 * t;
    const size_t base = (size_t)n * HH + jj;
    float2 pv = *(float2*)(p + base);
    float2 ci2 = *(const float2*)(Ci + base);
    float2 cf2 = *(const float2*)(Cf + base);
    float2 cg2 = *(const float2*)(Cg + base);
    float2 vi = {0.f, 0.f}, vf = {0.f, 0.f}, vg = {0.f, 0.f};
    #pragma unroll
    for (int s = 0; s < VSLAB; ++s) {
        const float* Vr = Vp + (size_t)s * (NB * K3H) + (size_t)n * K3H;
        float2 a = *(const float2*)(Vr + jj);
        float2 b = *(const float2*)(Vr + 512 + jj);
        float2 c = *(const float2*)(Vr + 1024 + jj);
        vi.x += a.x; vi.y += a.y;
        vf.x += b.x; vf.y += b.y;
        vg.x += c.x; vg.y += c.y;
    }
    const float Apx = pv.x + ci2.x * vi.x + cf2.x * vf.x + cg2.x * vg.x;
    const float Apy = pv.y + ci2.y * vi.y + cf2.y * vf.y + cg2.y * vg.y;
    red[t] = pv.x * Apx + pv.y * Apy;
    __syncthreads();
    for (int s = 128; s > 0; s >>= 1) { if (t < s) red[t] += red[t + s]; __syncthreads(); }
    if (t == 0) sA = rho[n] / fmaxf(red[0], 1e-30f);
    __syncthreads();
    const float alpha = sA;
    float2 xv = *(float2*)(xsol + base);
    xv.x += alpha * pv.x; xv.y += alpha * pv.y;
    *(float2*)(xsol + base) = xv;
    float2 rv = *(float2*)(r + base);
    rv.x -= alpha * Apx; rv.y -= alpha * Apy;
    *(float2*)(r + base) = rv;
    red[t] = rv.x * rv.x + rv.y * rv.y;
    __syncthreads();
    for (int s = 128; s > 0; s >>= 1) { if (t < s) red[t] += red[t + s]; __syncthreads(); }
    if (t == 0) { const float rr = red[0]; sB2 = rr / fmaxf(rho[n], 1e-30f); rho[n] = rr; }
    __syncthreads();
    const float beta = sB2;
    pv.x = rv.x + beta * pv.x; pv.y = rv.y + beta * pv.y;
    *(float2*)(p + base) = pv;
    unsigned short* Ur = U + (size_t)n * K3H;
    ushort2v ui, uf2, ug2;
    ui[0]  = f2bf(ci2.x * pv.x); ui[1]  = f2bf(ci2.y * pv.y);
    uf2[0] = f2bf(cf2.x * pv.x); uf2[1] = f2bf(cf2.y * pv.y);
    ug2[0] = f2bf(cg2.x * pv.x); ug2[1] = f2bf(cg2.y * pv.y);
    *(ushort2v*)(Ur + jj)        = ui;
    *(ushort2v*)(Ur + 512 + jj)  = uf2;
    *(ushort2v*)(Ur + 1024 + jj) = ug2;
    if (writeOut) {
        float2 o2; o2.x = xv.x; o2.y = xv.y;
        *(float2*)(outProx + base) = o2;
    }
}

// ---------------------------------------------------------------------------
extern "C" void kernel_launch(void* const* d_in, const int* in_sizes, int n_in,
                              void* d_out, int out_size, void* d_ws, size_t ws_size,
                              hipStream_t stream) {
    const float* x   = (const float*)d_in[0];
    const float* hx  = (const float*)d_in[1];
    const float* cx  = (const float*)d_in[2];
    const float* Wih = (const float*)d_in[3];
    const float* Whh = (const float*)d_in[4];
    const float* bih = (const float*)d_in[5];
    const float* bhh = (const float*)d_in[6];
    float* out = (float*)d_out;              // [h_new (131072) | prox_c (131072)]

    float* ws = (float*)d_ws;
    float* zp   = ws;                                  // 2*256*2048 = 1,048,576 f
    float* Ci   = zp + 2 * NB * 2048;
    float* Cf   = Ci + NH;
    float* Cg   = Cf + NH;
    float* xsol = Cg + NH;
    float* r    = xsol + NH;
    float* p    = r + NH;
    float* Vp   = p + NH;                              // VSLAB * 256*1536 f
    float* rho  = Vp + (size_t)VSLAB * NB * K3H;       // 256 f
    unsigned short* Wihb = (unsigned short*)(rho + 256);   // 1,048,576 us
    unsigned short* Whhb = Wihb + 2048 * 512;              // 1,048,576 us
    unsigned short* xb   = Whhb + 2048 * 512;              //   131,072 us
    unsigned short* hxb  = xb + NB * DD;                   //   131,072 us
    unsigned short* U    = hxb + NB * HH;                  //   393,216 us
    unsigned short* Mb   = U + NB * K3H;                   // 2,359,296 us

    k_cvt<<<2304, 256, 0, stream>>>(Wih, Whh, x, hx, Wihb, Whhb, xb, hxb);
    k_gemm_m<<<576, 256, 0, stream>>>(Wihb, Mb);
    k_gemm_z<<<dim3(32, 4, 2), 256, 0, stream>>>(xb, hxb, Wihb, Whhb, zp);
    k_gates_init<<<NB, 256, 0, stream>>>(zp, cx, bih, bhh, out,
                                         Ci, Cf, Cg, xsol, r, p, U, rho);

    for (int it = 0; it < CG_ITERS; ++it) {
        k_gemm_v<<<dim3(24, 4, VSLAB), 256, 0, stream>>>(U, Mb, Vp);
        k_cg_update<<<NB, 256, 0, stream>>>(xsol, r, p, Ci, Cf, Cg, Vp, rho, U,
                                            out + NH, (it == CG_ITERS - 1) ? 1 : 0);
    }
}

// Round 8
// 222.566 us; speedup vs baseline: 6.0545x; 1.2192x over previous
//
#include <hip/hip_runtime.h>
#include <math.h>

// Problem constants (reference: N=256, D=512, H=512, EPS=1.0)
#define NB   256
#define DD   512
#define HH   512
#define NH   (NB * HH)        // 131072
#define K3H  1536
#define CG_ITERS 8
#define VSLAB 8               // K-split of the V GEMM (1536 -> 8 x 192)

typedef __attribute__((ext_vector_type(8))) short   short8v;   // 8 x bf16 (4 VGPR)
typedef __attribute__((ext_vector_type(4))) float   f32x4;     // MFMA acc
typedef __attribute__((ext_vector_type(2))) unsigned short ushort2v;

__device__ __forceinline__ float sigmoidf_(float v) { return 1.0f / (1.0f + expf(-v)); }

// fp32 -> bf16 round-to-nearest-even
__device__ __forceinline__ unsigned short f2bf(float f) {
    union { float f; unsigned int u; } v; v.f = f;
    return (unsigned short)((v.u + 0x7FFFu + ((v.u >> 16) & 1u)) >> 16);
}

// Load 8 fp32 and convert to 8 bf16
__device__ __forceinline__ short8v ld8_f2bf(const float* p) {
    float4 a0 = *(const float4*)p;
    float4 a1 = *(const float4*)(p + 4);
    short8v o;
    o[0] = (short)f2bf(a0.x); o[1] = (short)f2bf(a0.y);
    o[2] = (short)f2bf(a0.z); o[3] = (short)f2bf(a0.w);
    o[4] = (short)f2bf(a1.x); o[5] = (short)f2bf(a1.y);
    o[6] = (short)f2bf(a1.z); o[7] = (short)f2bf(a1.w);
    return o;
}

// Swizzled LDS index (in shorts) for 64-col bf16 rows, 16B slots: <=2-way (free).
__device__ __forceinline__ int swz(int row, int col8) {
    return row * 64 + ((col8 ^ (row & 7)) << 3);
}

// ---------------------------------------------------------------------------
// Prep (MFMA): M = W13 @ W13^T (1536x1536) in bf16; stages fp32->bf16 inline.
// Grid 576 blocks.
// ---------------------------------------------------------------------------
__global__ __launch_bounds__(256) void k_gemm_m(
    const float* __restrict__ Wih, unsigned short* __restrict__ Mb)
{
    __shared__ unsigned short As[4096];
    __shared__ unsigned short Bs[4096];
    const int r0 = (blockIdx.x / 24) * 64;
    const int c0 = (blockIdx.x % 24) * 64;
    const int t = threadIdx.x;
    const int w = t >> 6, lane = t & 63;
    const int wm = (w >> 1) * 32, wc = (w & 1) * 32;
    const int fr = lane & 15, g = lane >> 4;
    const int srow = t >> 3, scol8 = t & 7;
    f32x4 acc[2][2] = {};
    for (int st = 0; st < 8; ++st) {
        const int kk = st * 64;
        #pragma unroll
        for (int pp = 0; pp < 2; ++pp) {
            const int row = pp * 32 + srow;
            As[0]; // keep layout
            *(short8v*)&As[swz(row, scol8)] =
                ld8_f2bf(Wih + (size_t)(r0 + row) * DD + kk + scol8 * 8);
            *(short8v*)&Bs[swz(row, scol8)] =
                ld8_f2bf(Wih + (size_t)(c0 + row) * DD + kk + scol8 * 8);
        }
        __syncthreads();
        #pragma unroll
        for (int ks2 = 0; ks2 < 2; ++ks2) {
            short8v a[2], b[2];
            #pragma unroll
            for (int i = 0; i < 2; ++i) {
                a[i] = *(const short8v*)&As[swz(wm + i * 16 + fr, ks2 * 4 + g)];
                b[i] = *(const short8v*)&Bs[swz(wc + i * 16 + fr, ks2 * 4 + g)];
            }
            #pragma unroll
            for (int i = 0; i < 2; ++i)
                #pragma unroll
                for (int jj = 0; jj < 2; ++jj)
                    acc[i][jj] = __builtin_amdgcn_mfma_f32_16x16x32_bf16(a[i], b[jj], acc[i][jj], 0, 0, 0);
        }
        __syncthreads();
    }
    #pragma unroll
    for (int i = 0; i < 2; ++i)
        #pragma unroll
        for (int jj = 0; jj < 2; ++jj)
            #pragma unroll
            for (int rg = 0; rg < 4; ++rg) {
                const int r = r0 + wm + i * 16 + g * 4 + rg;
                const int c = c0 + wc + jj * 16 + fr;
                Mb[(size_t)r * K3H + c] = f2bf(acc[i][jj][rg]);
            }
}

// ---------------------------------------------------------------------------
// Kernel Z (MFMA): zp[sl][n][c] = partial of [x|hx] @ [Wih|Whh]^T
// Stages fp32->bf16 inline. Tile 64n x 64c, K=1024 split 2. Grid (32,4,2).
// ---------------------------------------------------------------------------
__global__ __launch_bounds__(256) void k_gemm_z(
    const float* __restrict__ x, const float* __restrict__ hx,
    const float* __restrict__ Wih, const float* __restrict__ Whh,
    float* __restrict__ zp)
{
    __shared__ unsigned short As[4096];
    __shared__ unsigned short Bs[4096];
    const int j0 = blockIdx.x * 64;
    const int n0 = blockIdx.y * 64;
    const int sl = blockIdx.z;
    const int t = threadIdx.x;
    const int w = t >> 6, lane = t & 63;
    const int wm = (w >> 1) * 32, wjn = (w & 1) * 32;
    const int fr = lane & 15, g = lane >> 4;
    const int srow = t >> 3, scol8 = t & 7;
    const float* Asrc = sl ? hx : x;
    const float* Bsrc = sl ? Whh : Wih;
    f32x4 acc[2][2] = {};
    for (int st = 0; st < 8; ++st) {
        const int kk = st * 64;
        #pragma unroll
        for (int pp = 0; pp < 2; ++pp) {
            const int row = pp * 32 + srow;
            *(short8v*)&As[swz(row, scol8)] =
                ld8_f2bf(Asrc + (size_t)(n0 + row) * DD + kk + scol8 * 8);
            *(short8v*)&Bs[swz(row, scol8)] =
                ld8_f2bf(Bsrc + (size_t)(j0 + row) * DD + kk + scol8 * 8);
        }
        __syncthreads();
        #pragma unroll
        for (int ks2 = 0; ks2 < 2; ++ks2) {
            short8v a[2], b[2];
            #pragma unroll
            for (int i = 0; i < 2; ++i) {
                a[i] = *(const short8v*)&As[swz(wm  + i * 16 + fr, ks2 * 4 + g)];
                b[i] = *(const short8v*)&Bs[swz(wjn + i * 16 + fr, ks2 * 4 + g)];
            }
            #pragma unroll
            for (int i = 0; i < 2; ++i)
                #pragma unroll
                for (int jj = 0; jj < 2; ++jj)
                    acc[i][jj] = __builtin_amdgcn_mfma_f32_16x16x32_bf16(a[i], b[jj], acc[i][jj], 0, 0, 0);
        }
        __syncthreads();
    }
    float* Z = zp + (size_t)sl * NB * 2048;
    #pragma unroll
    for (int i = 0; i < 2; ++i)
        #pragma unroll
        for (int jj = 0; jj < 2; ++jj)
            #pragma unroll
            for (int rg = 0; rg < 4; ++rg) {
                const int n = n0 + wm + i * 16 + g * 4 + rg;
                const int c = j0 + wjn + jj * 16 + fr;
                Z[(size_t)n * 2048 + c] = acc[i][jj][rg];
            }
}

// ---------------------------------------------------------------------------
// Gates + CG init. Block n, thread handles j = 2t, 2t+1.
// Writes h_new, Ci/Cf/Cg, xsol=0, r=p=c_new, rho, U = C .* p (bf16).
// ---------------------------------------------------------------------------
__global__ __launch_bounds__(256) void k_gates_init(
    const float* __restrict__ zp, const float* __restrict__ cx,
    const float* __restrict__ bih, const float* __restrict__ bhh,
    float* __restrict__ hOut,
    float* __restrict__ Ci, float* __restrict__ Cf, float* __restrict__ Cg,
    float* __restrict__ xsol, float* __restrict__ r, float* __restrict__ p,
    unsigned short* __restrict__ U, float* __restrict__ rho)
{
    __shared__ float red[256];
    const int n = blockIdx.x, t = threadIdx.x;
    const int jj = 2 * t;
    const float* z0 = zp + (size_t)n * 2048;
    const float* z1 = zp + (size_t)(NB + n) * 2048;
    float part = 0.0f;
    float2 cn2, ci2, cf2, cg2;
    {
        #pragma unroll
        for (int e = 0; e < 2; ++e) {
            const int h = jj + e;
            const float zi = z0[h]        + z1[h]        + bih[h]        + bhh[h];
            const float zf = z0[512 + h]  + z1[512 + h]  + bih[512 + h]  + bhh[512 + h];
            const float zg = z0[1024 + h] + z1[1024 + h] + bih[1024 + h] + bhh[1024 + h];
            const float zo = z0[1536 + h] + z1[1536 + h] + bih[1536 + h] + bhh[1536 + h];
            const float iv = sigmoidf_(zi), fv = sigmoidf_(zf);
            const float gv = tanhf(zg),     ov = sigmoidf_(zo);
            const float cxv = cx[(size_t)n * HH + h];
            const float cn = fv * cxv + iv * gv;
            hOut[(size_t)n * HH + h] = ov * tanhf(cn);
            ((float*)&cn2)[e] = cn;
            ((float*)&ci2)[e] = iv * (1.0f - iv) * gv;
            ((float*)&cf2)[e] = fv * (1.0f - fv) * cxv;
            ((float*)&cg2)[e] = (1.0f - gv * gv) * iv;
            part += cn * cn;
        }
    }
    const size_t base = (size_t)n * HH + jj;
    *(float2*)(Ci + base) = ci2;
    *(float2*)(Cf + base) = cf2;
    *(float2*)(Cg + base) = cg2;
    float2 zero2; zero2.x = 0.0f; zero2.y = 0.0f;
    *(float2*)(xsol + base) = zero2;
    *(float2*)(r + base) = cn2;
    *(float2*)(p + base) = cn2;
    unsigned short* Ur = U + (size_t)n * K3H;
    ushort2v ui, uf, ug;
    ui[0] = f2bf(ci2.x * cn2.x); ui[1] = f2bf(ci2.y * cn2.y);
    uf[0] = f2bf(cf2.x * cn2.x); uf[1] = f2bf(cf2.y * cn2.y);
    ug[0] = f2bf(cg2.x * cn2.x); ug[1] = f2bf(cg2.y * cn2.y);
    *(ushort2v*)(Ur + jj)        = ui;
    *(ushort2v*)(Ur + 512 + jj)  = uf;
    *(ushort2v*)(Ur + 1024 + jj) = ug;
    red[t] = part; __syncthreads();
    for (int s = 128; s > 0; s >>= 1) { if (t < s) red[t] += red[t + s]; __syncthreads(); }
    if (t == 0) rho[n] = red[0];
}

// ---------------------------------------------------------------------------
// In-loop GEMM: Vp[sl][n][c] = partial of U @ Mb^T  (M symmetric, bf16).
// K=1536 split into VSLAB=8 slabs of 192 (3 stages of 64).
// Grid (24 c-tiles, 4 n-tiles, 8 slabs) = 768 blocks.
// ---------------------------------------------------------------------------
__global__ __launch_bounds__(256) void k_gemm_v(
    const unsigned short* __restrict__ U,
    const unsigned short* __restrict__ Mb,
    float* __restrict__ Vp)
{
    __shared__ unsigned short As[4096];
    __shared__ unsigned short Bs[4096];
    const int c0 = blockIdx.x * 64;
    const int n0 = blockIdx.y * 64;
    const int sl = blockIdx.z;
    const int t = threadIdx.x;
    const int w = t >> 6, lane = t & 63;
    const int wm = (w >> 1) * 32, wc = (w & 1) * 32;
    const int fr = lane & 15, g = lane >> 4;
    const int srow = t >> 3, scol8 = t & 7;
    f32x4 acc[2][2] = {};
    for (int st = 0; st < 3; ++st) {
        const int kb = sl * 192 + st * 64;
        #pragma unroll
        for (int pp = 0; pp < 2; ++pp) {
            const int row = pp * 32 + srow;
            *(short8v*)&As[swz(row, scol8)] =
                *(const short8v*)(U + (size_t)(n0 + row) * K3H + kb + scol8 * 8);
            *(short8v*)&Bs[swz(row, scol8)] =
                *(const short8v*)(Mb + (size_t)(c0 + row) * K3H + kb + scol8 * 8);
        }
        __syncthreads();
        #pragma unroll
        for (int ks2 = 0; ks2 < 2; ++ks2) {
            short8v a[2], b[2];
            #pragma unroll
            for (int i = 0; i < 2; ++i) {
                a[i] = *(const short8v*)&As[swz(wm + i * 16 + fr, ks2 * 4 + g)];
                b[i] = *(const short8v*)&Bs[swz(wc + i * 16 + fr, ks2 * 4 + g)];
            }
            #pragma unroll
            for (int i = 0; i < 2; ++i)
                #pragma unroll
                for (int q = 0; q < 2; ++q)
                    acc[i][q] = __builtin_amdgcn_mfma_f32_16x16x32_bf16(a[i], b[q], acc[i][q], 0, 0, 0);
        }
        __syncthreads();
    }
    float* Vs = Vp + (size_t)sl * (NB * K3H);
    #pragma unroll
    for (int i = 0; i < 2; ++i)
        #pragma unroll
        for (int q = 0; q < 2; ++q)
            #pragma unroll
            for (int rg = 0; rg < 4; ++rg) {
                const int nn = n0 + wm + i * 16 + g * 4 + rg;
                const int cc = c0 + wc + q * 16 + fr;
                Vs[(size_t)nn * K3H + cc] = acc[i][q][rg];
            }
}

// ---------------------------------------------------------------------------
// CG vector step. Block n, thread handles j = 2t, 2t+1.
// ---------------------------------------------------------------------------
__global__ __launch_bounds__(256) void k_cg_update(
    float* __restrict__ xsol, float* __restrict__ r, float* __restrict__ p,
    const float* __restrict__ Ci, const float* __restrict__ Cf, const float* __restrict__ Cg,
    const float* __restrict__ Vp, float* __restrict__ rho,
    unsigned short* __restrict__ U, float* __restrict__ outProx, int writeOut)
{
    __shared__ float red[256];
    __shared__ float sA, sB2;
    const int n = blockIdx.x, t = threadIdx.x;
    const int jj = 2 * t;
    const size_t base = (size_t)n * HH + jj;
    float2 pv = *(float2*)(p + base);
    float2 ci2 = *(const float2*)(Ci + base);
    float2 cf2 = *(const float2*)(Cf + base);
    float2 cg2 = *(const float2*)(Cg + base);
    float2 vi = {0.f, 0.f}, vf = {0.f, 0.f}, vg = {0.f, 0.f};
    #pragma unroll
    for (int s = 0; s < VSLAB; ++s) {
        const float* Vr = Vp + (size_t)s * (NB * K3H) + (size_t)n * K3H;
        float2 a = *(const float2*)(Vr + jj);
        float2 b = *(const float2*)(Vr + 512 + jj);
        float2 c = *(const float2*)(Vr + 1024 + jj);
        vi.x += a.x; vi.y += a.y;
        vf.x += b.x; vf.y += b.y;
        vg.x += c.x; vg.y += c.y;
    }
    const float Apx = pv.x + ci2.x * vi.x + cf2.x * vf.x + cg2.x * vg.x;
    const float Apy = pv.y + ci2.y * vi.y + cf2.y * vf.y + cg2.y * vg.y;
    red[t] = pv.x * Apx + pv.y * Apy;
    __syncthreads();
    for (int s = 128; s > 0; s >>= 1) { if (t < s) red[t] += red[t + s]; __syncthreads(); }
    if (t == 0) sA = rho[n] / fmaxf(red[0], 1e-30f);
    __syncthreads();
    const float alpha = sA;
    float2 xv = *(float2*)(xsol + base);
    xv.x += alpha * pv.x; xv.y += alpha * pv.y;
    *(float2*)(xsol + base) = xv;
    float2 rv = *(float2*)(r + base);
    rv.x -= alpha * Apx; rv.y -= alpha * Apy;
    *(float2*)(r + base) = rv;
    red[t] = rv.x * rv.x + rv.y * rv.y;
    __syncthreads();
    for (int s = 128; s > 0; s >>= 1) { if (t < s) red[t] += red[t + s]; __syncthreads(); }
    if (t == 0) { const float rr = red[0]; sB2 = rr / fmaxf(rho[n], 1e-30f); rho[n] = rr; }
    __syncthreads();
    const float beta = sB2;
    pv.x = rv.x + beta * pv.x; pv.y = rv.y + beta * pv.y;
    *(float2*)(p + base) = pv;
    unsigned short* Ur = U + (size_t)n * K3H;
    ushort2v ui, uf2, ug2;
    ui[0]  = f2bf(ci2.x * pv.x); ui[1]  = f2bf(ci2.y * pv.y);
    uf2[0] = f2bf(cf2.x * pv.x); uf2[1] = f2bf(cf2.y * pv.y);
    ug2[0] = f2bf(cg2.x * pv.x); ug2[1] = f2bf(cg2.y * pv.y);
    *(ushort2v*)(Ur + jj)        = ui;
    *(ushort2v*)(Ur + 512 + jj)  = uf2;
    *(ushort2v*)(Ur + 1024 + jj) = ug2;
    if (writeOut) {
        float2 o2; o2.x = xv.x; o2.y = xv.y;
        *(float2*)(outProx + base) = o2;
    }
}

// ---------------------------------------------------------------------------
extern "C" void kernel_launch(void* const* d_in, const int* in_sizes, int n_in,
                              void* d_out, int out_size, void* d_ws, size_t ws_size,
                              hipStream_t stream) {
    const float* x   = (const float*)d_in[0];
    const float* hx  = (const float*)d_in[1];
    const float* cx  = (const float*)d_in[2];
    const float* Wih = (const float*)d_in[3];
    const float* Whh = (const float*)d_in[4];
    const float* bih = (const float*)d_in[5];
    const float* bhh = (const float*)d_in[6];
    float* out = (float*)d_out;              // [h_new (131072) | prox_c (131072)]

    float* ws = (float*)d_ws;
    float* zp   = ws;                                  // 2*256*2048 = 1,048,576 f
    float* Ci   = zp + 2 * NB * 2048;
    float* Cf   = Ci + NH;
    float* Cg   = Cf + NH;
    float* xsol = Cg + NH;
    float* r    = xsol + NH;
    float* p    = r + NH;
    float* Vp   = p + NH;                              // VSLAB * 256*1536 f
    float* rho  = Vp + (size_t)VSLAB * NB * K3H;       // 256 f
    unsigned short* U  = (unsigned short*)(rho + 256); //   393,216 us
    unsigned short* Mb = U + NB * K3H;                 // 2,359,296 us

    k_gemm_m<<<576, 256, 0, stream>>>(Wih, Mb);
    k_gemm_z<<<dim3(32, 4, 2), 256, 0, stream>>>(x, hx, Wih, Whh, zp);
    k_gates_init<<<NB, 256, 0, stream>>>(zp, cx, bih, bhh, out,
                                         Ci, Cf, Cg, xsol, r, p, U, rho);

    for (int it = 0; it < CG_ITERS; ++it) {
        k_gemm_v<<<dim3(24, 4, VSLAB), 256, 0, stream>>>(U, Mb, Vp);
        k_cg_update<<<NB, 256, 0, stream>>>(xsol, r, p, Ci, Cf, Cg, Vp, rho, U,
                                            out + NH, (it == CG_ITERS - 1) ? 1 : 0);
    }
}